// Round 1
// baseline (45.340 us; speedup 1.0000x reference)
//
#include <hip/hip_runtime.h>

#define ROW_LEN 4096
#define N_ROWS  8192
#define BETA    1e-7f

// ---------------- Kernel 1: per-row Pearson loss ----------------
// One 256-thread block per row. Single pass over the row computing the
// 5 uncentered moments, then:
//   num = Sxy - Sx*Sy/T
//   xx  = Sxx - Sx^2/T
//   yy  = Syy - Sy^2/T
//   p   = 1 - num / (sqrt(xx+BETA)*sqrt(yy+BETA))
__global__ __launch_bounds__(256) void row_pearson_kernel(
    const float* __restrict__ x, const float* __restrict__ y,
    float* __restrict__ p_row) {
    const int row = blockIdx.x;
    const int tid = threadIdx.x;

    const float4* __restrict__ xr =
        reinterpret_cast<const float4*>(x + (size_t)row * ROW_LEN);
    const float4* __restrict__ yr =
        reinterpret_cast<const float4*>(y + (size_t)row * ROW_LEN);

    float sx = 0.f, sy = 0.f, sxy = 0.f, sxx = 0.f, syy = 0.f;

#pragma unroll
    for (int i = 0; i < 4; ++i) {
        float4 a = xr[tid + i * 256];
        float4 b = yr[tid + i * 256];
        sx  += a.x + a.y + a.z + a.w;
        sy  += b.x + b.y + b.z + b.w;
        sxy += a.x * b.x + a.y * b.y + a.z * b.z + a.w * b.w;
        sxx += a.x * a.x + a.y * a.y + a.z * a.z + a.w * a.w;
        syy += b.x * b.x + b.y * b.y + b.z * b.z + b.w * b.w;
    }

    // Wave-64 butterfly-free shfl_down reduction (deterministic order).
#pragma unroll
    for (int off = 32; off > 0; off >>= 1) {
        sx  += __shfl_down(sx, off);
        sy  += __shfl_down(sy, off);
        sxy += __shfl_down(sxy, off);
        sxx += __shfl_down(sxx, off);
        syy += __shfl_down(syy, off);
    }

    __shared__ float red[4][5];  // 4 waves x 5 moments
    const int wave = tid >> 6;
    const int lane = tid & 63;
    if (lane == 0) {
        red[wave][0] = sx;
        red[wave][1] = sy;
        red[wave][2] = sxy;
        red[wave][3] = sxx;
        red[wave][4] = syy;
    }
    __syncthreads();

    if (tid == 0) {
        float Sx = 0.f, Sy = 0.f, Sxy = 0.f, Sxx = 0.f, Syy = 0.f;
#pragma unroll
        for (int w = 0; w < 4; ++w) {
            Sx  += red[w][0];
            Sy  += red[w][1];
            Sxy += red[w][2];
            Sxx += red[w][3];
            Syy += red[w][4];
        }
        const float invT = 1.0f / (float)ROW_LEN;
        float num = Sxy - Sx * Sy * invT;
        float xx  = Sxx - Sx * Sx * invT;
        float yy  = Syy - Sy * Sy * invT;
        float den = sqrtf(xx + BETA) * sqrtf(yy + BETA);
        p_row[row] = 1.0f - num / den;
    }
}

// ---------------- Kernel 2: deterministic mean over rows ----------------
__global__ __launch_bounds__(256) void mean_kernel(
    const float* __restrict__ p_row, float* __restrict__ out) {
    const int tid = threadIdx.x;
    float s = 0.f;
#pragma unroll
    for (int i = 0; i < N_ROWS / 256; ++i) {
        s += p_row[tid + i * 256];
    }
#pragma unroll
    for (int off = 32; off > 0; off >>= 1) {
        s += __shfl_down(s, off);
    }
    __shared__ float red[4];
    const int wave = tid >> 6;
    const int lane = tid & 63;
    if (lane == 0) red[wave] = s;
    __syncthreads();
    if (tid == 0) {
        float tot = red[0] + red[1] + red[2] + red[3];
        out[0] = tot * (1.0f / (float)N_ROWS);
    }
}

extern "C" void kernel_launch(void* const* d_in, const int* in_sizes, int n_in,
                              void* d_out, int out_size, void* d_ws, size_t ws_size,
                              hipStream_t stream) {
    const float* predict = (const float*)d_in[0];
    const float* target  = (const float*)d_in[1];
    float* out   = (float*)d_out;
    float* p_row = (float*)d_ws;  // N_ROWS floats = 32 KiB scratch

    row_pearson_kernel<<<N_ROWS, 256, 0, stream>>>(predict, target, p_row);
    mean_kernel<<<1, 256, 0, stream>>>(p_row, out);
}